// Round 2
// baseline (9420.876 us; speedup 1.0000x reference)
//
#include <hip/hip_runtime.h>
#include <math.h>

#define HWp 65536
#define Wp 256

__device__ __forceinline__ float apply_act(float v, int ACT) {
    if (ACT == 1) return fmaxf(v, 0.f);
    if (ACT == 2) return (v > 0.f) ? v : 0.01f * v;
    return v;
}

// Generic direct 3x3 conv, dilation DIL, pad DIL (same-size), NCHW f32.
// Input is logical concat of in0 (C0 ch) and in1 (C1 ch). Cout fixed 32.
// Block: 256 thr = 64 w-quads x 4 rows. Grid: B * 32 * (H/4) = 16384.
template<int DIL, int ACT>
__global__ __launch_bounds__(256) void conv3x3_k(
    const float* __restrict__ in0, int C0, int b0s,
    const float* __restrict__ in1, int C1, int b1s,
    const float* __restrict__ wgt, const float* __restrict__ bias,
    float* __restrict__ out, int obs)
{
    const int Cin = C0 + C1;
    __shared__ float swgt[33 * 9];
    int tid = threadIdx.x;
    int blk = blockIdx.x;
    int hg = blk & 63;
    int co = (blk >> 6) & 31;
    int b  = blk >> 11;
    for (int i = tid; i < Cin * 9; i += 256) swgt[i] = wgt[co * Cin * 9 + i];
    __syncthreads();
    int h  = hg * 4 + (tid >> 6);
    int w0 = (tid & 63) << 2;
    float acc[4] = {0.f, 0.f, 0.f, 0.f};
    for (int ic = 0; ic < Cin; ++ic) {
        const float* plane = (ic < C0)
            ? (in0 + (size_t)b * b0s + (size_t)ic * HWp)
            : (in1 + (size_t)b * b1s + (size_t)(ic - C0) * HWp);
        const float* wk = &swgt[ic * 9];
        #pragma unroll
        for (int kh = 0; kh < 3; ++kh) {
            int r = h + (kh - 1) * DIL;
            if ((unsigned)r < 256u) {
                const float* row = plane + r * Wp;
                float v[4 + 2 * DIL];
                #pragma unroll
                for (int j = 0; j < 4 + 2 * DIL; ++j) {
                    int ww = w0 - DIL + j;
                    v[j] = ((unsigned)ww < 256u) ? row[ww] : 0.f;
                }
                #pragma unroll
                for (int kw = 0; kw < 3; ++kw) {
                    float wv = wk[kh * 3 + kw];
                    #pragma unroll
                    for (int j = 0; j < 4; ++j)
                        acc[j] = fmaf(v[j + kw * DIL], wv, acc[j]);
                }
            }
        }
    }
    float bv = bias ? bias[co] : 0.f;
    float4 o;
    #pragma unroll
    for (int j = 0; j < 4; ++j)
        ((float*)&o)[j] = apply_act(acc[j] + bv, ACT);
    float* op = out + (size_t)b * obs + (size_t)co * HWp + h * Wp + w0;
    *reinterpret_cast<float4*>(op) = o;
}

// 1x1 conv over concat(in0,in1). Cout fixed 32. 4 px/thread, float4.
template<int ACT>
__global__ __launch_bounds__(256) void conv1x1_k(
    const float* __restrict__ in0, int C0, int b0s,
    const float* __restrict__ in1, int C1, int b1s,
    const float* __restrict__ wgt, const float* __restrict__ bias,
    float* __restrict__ out, int obs)
{
    const int Cin = C0 + C1;
    __shared__ float swgt[64];
    int tid = threadIdx.x;
    int blk = blockIdx.x;
    int pg = blk & 63;
    int co = (blk >> 6) & 31;
    int b  = blk >> 11;
    for (int i = tid; i < Cin; i += 256) swgt[i] = wgt[co * Cin + i];
    __syncthreads();
    int px = pg * 1024 + tid * 4;
    float a0 = 0.f, a1 = 0.f, a2 = 0.f, a3 = 0.f;
    for (int ic = 0; ic < Cin; ++ic) {
        const float* plane = (ic < C0)
            ? (in0 + (size_t)b * b0s + (size_t)ic * HWp)
            : (in1 + (size_t)b * b1s + (size_t)(ic - C0) * HWp);
        float4 v = *reinterpret_cast<const float4*>(plane + px);
        float wv = swgt[ic];
        a0 = fmaf(v.x, wv, a0); a1 = fmaf(v.y, wv, a1);
        a2 = fmaf(v.z, wv, a2); a3 = fmaf(v.w, wv, a3);
    }
    float bv = bias ? bias[co] : 0.f;
    float4 o;
    o.x = apply_act(a0 + bv, ACT); o.y = apply_act(a1 + bv, ACT);
    o.z = apply_act(a2 + bv, ACT); o.w = apply_act(a3 + bv, ACT);
    float* op = out + (size_t)b * obs + (size_t)co * HWp + px;
    *reinterpret_cast<float4*>(op) = o;
}

__global__ void sobel_prep_k(const float* __restrict__ base,
                             const float* __restrict__ factor,
                             float* __restrict__ swout)
{
    int i = blockIdx.x * 256 + threadIdx.x;
    if (i < 288) swout[i] = base[i] * factor[i / 9];
}

// gates = softmax(1x1 conv over concat(ex,ey,ez)); enh = sum g_k * e_k.
// Writes enh in place into ex. 1 px/thread; grid = B * 256.
__global__ __launch_bounds__(256) void fuse_k(
    float* __restrict__ ex, int exb,
    const float* __restrict__ ey, int eyb,
    const float* __restrict__ ez, int ezb,
    const float* __restrict__ gw_, const float* __restrict__ gb_)
{
    __shared__ float gw[288];
    __shared__ float gb[3];
    int tid = threadIdx.x;
    for (int i = tid; i < 288; i += 256) gw[i] = gw_[i];
    if (tid < 3) gb[tid] = gb_[tid];
    __syncthreads();
    int b = blockIdx.x >> 8;
    int px = ((blockIdx.x & 255) << 8) | tid;
    float vx[32], vy[32], vz[32];
    float g0 = gb[0], g1 = gb[1], g2 = gb[2];
    float* exp_ = ex + (size_t)b * exb + px;
    const float* eyp = ey + (size_t)b * eyb + px;
    const float* ezp = ez + (size_t)b * ezb + px;
    #pragma unroll
    for (int c = 0; c < 32; ++c) {
        vx[c] = exp_[(size_t)c * HWp];
        vy[c] = eyp[(size_t)c * HWp];
        vz[c] = ezp[(size_t)c * HWp];
        g0 = fmaf(gw[c], vx[c], g0);
        g0 = fmaf(gw[32 + c], vy[c], g0);
        g0 = fmaf(gw[64 + c], vz[c], g0);
        g1 = fmaf(gw[96 + c], vx[c], g1);
        g1 = fmaf(gw[128 + c], vy[c], g1);
        g1 = fmaf(gw[160 + c], vz[c], g1);
        g2 = fmaf(gw[192 + c], vx[c], g2);
        g2 = fmaf(gw[224 + c], vy[c], g2);
        g2 = fmaf(gw[256 + c], vz[c], g2);
    }
    float m = fmaxf(g0, fmaxf(g1, g2));
    float e0 = expf(g0 - m), e1 = expf(g1 - m), e2 = expf(g2 - m);
    float inv = 1.f / (e0 + e1 + e2);
    e0 *= inv; e1 *= inv; e2 *= inv;
    #pragma unroll
    for (int c = 0; c < 32; ++c)
        exp_[(size_t)c * HWp] = e0 * vx[c] + e1 * vy[c] + e2 * vz[c];
}

// Per-(b,c) mean & max over HxW. Grid = 256 blocks.
__global__ __launch_bounds__(256) void ca_reduce_k(
    const float* __restrict__ enh, int bstride,
    float* __restrict__ avg, float* __restrict__ mx)
{
    int bc = blockIdx.x;
    int b = bc >> 5, c = bc & 31;
    const float* p = enh + (size_t)b * bstride + (size_t)c * HWp;
    int tid = threadIdx.x;
    float s = 0.f, m = -1e30f;
    for (int i = tid * 4; i < HWp; i += 1024) {
        float4 v = *reinterpret_cast<const float4*>(p + i);
        s += v.x + v.y + v.z + v.w;
        m = fmaxf(m, fmaxf(fmaxf(v.x, v.y), fmaxf(v.z, v.w)));
    }
    #pragma unroll
    for (int off = 32; off; off >>= 1) {
        s += __shfl_down(s, off);
        m = fmaxf(m, __shfl_down(m, off));
    }
    __shared__ float ss[4], sm[4];
    if ((tid & 63) == 0) { ss[tid >> 6] = s; sm[tid >> 6] = m; }
    __syncthreads();
    if (tid == 0) {
        s = ss[0] + ss[1] + ss[2] + ss[3];
        m = fmaxf(fmaxf(sm[0], sm[1]), fmaxf(sm[2], sm[3]));
        avg[bc] = s * (1.f / 65536.f);
        mx[bc] = m;
    }
}

// Tiny channel-attention MLP. 1 block, 256 threads (t = b*32+c).
__global__ void ca_mlp_k(const float* __restrict__ avg, const float* __restrict__ mx,
                         const float* __restrict__ w1, const float* __restrict__ w2,
                         float* __restrict__ ca)
{
    int t = threadIdx.x;
    int b = t >> 5, c = t & 31;
    float hs[2];
    #pragma unroll
    for (int j = 0; j < 2; ++j) {
        float sa_ = 0.f, sm_ = 0.f;
        for (int k = 0; k < 32; ++k) {
            float w = w1[j * 32 + k];
            sa_ = fmaf(w, avg[b * 32 + k], sa_);
            sm_ = fmaf(w, mx[b * 32 + k], sm_);
        }
        hs[j] = fmaxf(sa_, 0.f) + fmaxf(sm_, 0.f);
    }
    float v = w2[c * 2 + 0] * hs[0] + w2[c * 2 + 1] * hs[1];
    ca[t] = 1.f / (1.f + expf(-v));
}

// Per-pixel channel mean/max of f = ca*enh. Grid = B*256.
__global__ __launch_bounds__(256) void samap_k(
    const float* __restrict__ enh, int bstride,
    const float* __restrict__ ca, float* __restrict__ smap)
{
    int b = blockIdx.x >> 8;
    int px = ((blockIdx.x & 255) << 8) | threadIdx.x;
    const float* base = enh + (size_t)b * bstride + px;
    float s = 0.f, m = -1e30f;
    #pragma unroll
    for (int c = 0; c < 32; ++c) {
        float v = base[(size_t)c * HWp] * ca[b * 32 + c];
        s += v;
        m = fmaxf(m, v);
    }
    smap[(size_t)b * 2 * HWp + px] = s * (1.f / 32.f);
    smap[(size_t)b * 2 * HWp + HWp + px] = m;
}

// 7x7 SA conv + sigmoid, then out0 = lrelu(out1 + sa*ca*enh) -> d_out lower.
// enh lives in d_out lower (same addresses written) — per-thread RAW only.
__global__ __launch_bounds__(256) void merge_k(
    const float* __restrict__ smap, const float* __restrict__ saw,
    const float* __restrict__ ca, const float* __restrict__ out1, int o1bs,
    float* __restrict__ dout)
{
    __shared__ float sw[98];
    int tid = threadIdx.x;
    for (int i = tid; i < 98; i += 256) sw[i] = saw[i];
    __syncthreads();
    int b = blockIdx.x >> 8;
    int px = ((blockIdx.x & 255) << 8) | tid;
    int h = px >> 8, w = px & 255;
    float acc = 0.f;
    const float* sm0 = smap + (size_t)b * 2 * HWp;
    #pragma unroll
    for (int ic = 0; ic < 2; ++ic) {
        #pragma unroll
        for (int kh = 0; kh < 7; ++kh) {
            int r = h + kh - 3;
            if ((unsigned)r < 256u) {
                #pragma unroll
                for (int kw = 0; kw < 7; ++kw) {
                    int cc = w + kw - 3;
                    if ((unsigned)cc < 256u)
                        acc = fmaf(sm0[(size_t)ic * HWp + r * Wp + cc],
                                   sw[ic * 49 + kh * 7 + kw], acc);
                }
            }
        }
    }
    float sa = 1.f / (1.f + expf(-acc));
    float* dbase = dout + (size_t)b * 64 * HWp + px;
    const float* obase = out1 + (size_t)b * o1bs + px;
    #pragma unroll
    for (int c = 0; c < 32; ++c) {
        float fv = ca[b * 32 + c] * dbase[(size_t)c * HWp];
        float o = obase[(size_t)c * HWp] + sa * fv;
        dbase[(size_t)c * HWp] = (o > 0.f) ? o : 0.01f * o;
    }
}

extern "C" void kernel_launch(void* const* d_in, const int* in_sizes, int n_in,
                              void* d_out, int out_size, void* d_ws, size_t ws_size,
                              hipStream_t stream)
{
    (void)in_sizes; (void)n_in; (void)out_size; (void)ws_size;
    const float* x        = (const float*)d_in[0];
    const float* sob_base = (const float*)d_in[1];
    const float* sob_fac  = (const float*)d_in[2];
    const float* sob_bias = (const float*)d_in[3];
    const float* f4_w = (const float*)d_in[4];   const float* f4_b = (const float*)d_in[5];
    const float* ec1_w = (const float*)d_in[6];  const float* ec1_b = (const float*)d_in[7];
    const float* ec2_w = (const float*)d_in[8];  const float* ec2_b = (const float*)d_in[9];
    const float* ec3_w = (const float*)d_in[10]; const float* ec3_b = (const float*)d_in[11];
    const float* gate_w = (const float*)d_in[12]; const float* gate_b = (const float*)d_in[13];
    const float* ca1_w = (const float*)d_in[14]; const float* ca2_w = (const float*)d_in[15];
    const float* sa_w  = (const float*)d_in[16];
    const float* p1_w = (const float*)d_in[17]; const float* p1_b = (const float*)d_in[18];
    const float* f1_w = (const float*)d_in[19]; const float* f1_b = (const float*)d_in[20];
    const float* p2_w = (const float*)d_in[21]; const float* p2_b = (const float*)d_in[22];
    const float* f2_w = (const float*)d_in[23]; const float* f2_b = (const float*)d_in[24];
    const float* p3_w = (const float*)d_in[25]; const float* p3_b = (const float*)d_in[26];
    const float* f3_w = (const float*)d_in[27]; const float* f3_b = (const float*)d_in[28];

    float* dout = (float*)d_out;
    float* ws = (float*)d_ws;
    // ws layout (floats): S[8*32*HW] | OUT1[8*32*HW] | SMAP[8*2*HW] | SW(288) | AVG(256) | MX(256) | CA(256)
    float* S    = ws;
    float* OUT1 = ws + (size_t)8 * 32 * HWp;
    float* SMAP = ws + (size_t)16 * 32 * HWp;
    float* SW   = SMAP + (size_t)8 * 2 * HWp;
    float* AVG  = SW + 288;
    float* MX   = AVG + 256;
    float* CA   = MX + 256;

    const int B32HW = 32 * HWp;   // batch stride of a [B,32,H,W] buffer
    const int B64HW = 64 * HWp;   // batch stride of d_out
    float* EX = dout;             // d_out lower half: ex, then enh in place
    float* EY = dout + 32 * HWp;  // d_out upper half: ey
    dim3 blk(256);
    dim3 g_conv(16384);           // B * 32 * (H/4)
    dim3 g_px(2048);              // B * 256 pixel blocks

    // 1) sobel weight prep
    sobel_prep_k<<<2, blk, 0, stream>>>(sob_base, sob_fac, SW);
    // 2) sobel conv: x -> S
    conv3x3_k<1, 0><<<g_conv, blk, 0, stream>>>(x, 1, HWp, nullptr, 0, 0, SW, sob_bias, S, B32HW);
    // 3) f4: concat(x, S) -> OUT1 (lrelu)
    conv3x3_k<1, 2><<<g_conv, blk, 0, stream>>>(x, 1, HWp, S, 32, B32HW, f4_w, f4_b, OUT1, B32HW);
    // 4-6) dilated edge convs (relu): ex->d_out lower, ey->d_out upper, ez->S
    conv3x3_k<1, 1><<<g_conv, blk, 0, stream>>>(OUT1, 32, B32HW, nullptr, 0, 0, ec1_w, ec1_b, EX, B64HW);
    conv3x3_k<2, 1><<<g_conv, blk, 0, stream>>>(OUT1, 32, B32HW, nullptr, 0, 0, ec2_w, ec2_b, EY, B64HW);
    conv3x3_k<3, 1><<<g_conv, blk, 0, stream>>>(OUT1, 32, B32HW, nullptr, 0, 0, ec3_w, ec3_b, S, B32HW);
    // 7) gate softmax + blend -> enh (in place in EX = d_out lower)
    fuse_k<<<g_px, blk, 0, stream>>>(EX, B64HW, EY, B64HW, S, B32HW, gate_w, gate_b);
    // 8-9) channel attention
    ca_reduce_k<<<256, blk, 0, stream>>>(EX, B64HW, AVG, MX);
    ca_mlp_k<<<1, blk, 0, stream>>>(AVG, MX, ca1_w, ca2_w, CA);
    // 10) spatial attention input maps
    samap_k<<<g_px, blk, 0, stream>>>(EX, B64HW, CA, SMAP);
    // 11) 7x7 SA conv + residual merge -> out0 into d_out lower
    merge_k<<<g_px, blk, 0, stream>>>(SMAP, sa_w, CA, OUT1, B32HW, dout);
    // 12-17) dense cascade
    conv1x1_k<2><<<g_conv, blk, 0, stream>>>(dout, 32, B64HW, nullptr, 0, 0, p1_w, p1_b, OUT1, B32HW);
    conv3x3_k<1, 2><<<g_conv, blk, 0, stream>>>(OUT1, 32, B32HW, nullptr, 0, 0, f1_w, f1_b, S, B32HW);
    conv1x1_k<2><<<g_conv, blk, 0, stream>>>(dout, 32, B64HW, S, 32, B32HW, p2_w, p2_b, OUT1, B32HW);
    conv3x3_k<1, 2><<<g_conv, blk, 0, stream>>>(OUT1, 32, B32HW, nullptr, 0, 0, f2_w, f2_b, S, B32HW);
    conv1x1_k<2><<<g_conv, blk, 0, stream>>>(dout, 32, B64HW, S, 32, B32HW, p3_w, p3_b, OUT1, B32HW);
    conv3x3_k<1, 2><<<g_conv, blk, 0, stream>>>(OUT1, 32, B32HW, nullptr, 0, 0, f3_w, f3_b, dout + 32 * HWp, B64HW);
}

// Round 3
// 537.899 us; speedup vs baseline: 17.5142x; 17.5142x over previous
//
#include <hip/hip_runtime.h>
#include <math.h>

typedef unsigned short u16;
typedef short short8 __attribute__((ext_vector_type(8)));
typedef float f32x4 __attribute__((ext_vector_type(4)));
typedef unsigned short ushort4v __attribute__((ext_vector_type(4)));

#define Hh 256
#define Ww 256
#define Bb 8
#define PW 262
#define PAD 3
#define HPW (Hh * PW)

__device__ __forceinline__ float bf2f(u16 v) {
    unsigned u = ((unsigned)v) << 16;
    union { unsigned u; float f; } c; c.u = u; return c.f;
}
__device__ __forceinline__ u16 f2bf(float f) {
    union { float f; unsigned u; } c; c.f = f;
    unsigned lsb = (c.u >> 16) & 1u;
    c.u += 0x7fffu + lsb;
    return (u16)(c.u >> 16);
}
__device__ __forceinline__ float sigm(float v) { return 1.f / (1.f + expf(-v)); }

// ---------------- MFMA implicit-GEMM conv ----------------
// NHWC bf16, padded W (PW=262, interior at +PAD). M=32 co (2 frags),
// N=64 px/wave (4 frags), K = TAPS*ICB*32 (K-step = one tap x 32ch).
// A prepacked in fragment order: apack[(s*2+mf)*64 + lane][8].
// TWO: concat of two 32-ch sources (icb selects pointer).
template<int TAPS, int ICB, int DIL, int ACT, bool TWO>
__global__ __launch_bounds__(256) void convm_k(
    const u16* __restrict__ in0, const u16* __restrict__ in1,
    const u16* __restrict__ apack, const float* __restrict__ bias,
    u16* __restrict__ out)
{
    constexpr int CS = TWO ? 32 : ICB * 32;  // px stride (elems) of source
    const int tid  = threadIdx.x;
    const int lane = tid & 63;
    const int wv   = tid >> 6;
    const int h    = blockIdx.x & 255;
    const int b    = blockIdx.x >> 8;
    const int nl   = (wv << 6) + (lane & 15);  // px col base for this lane
    const int icg  = lane >> 4;                // 0..3

    f32x4 acc[2][4];
    #pragma unroll
    for (int mf = 0; mf < 2; ++mf)
        #pragma unroll
        for (int nf = 0; nf < 4; ++nf)
            acc[mf][nf] = (f32x4){0.f, 0.f, 0.f, 0.f};

    #pragma unroll
    for (int s = 0; s < TAPS * ICB; ++s) {
        const int tap = s / ICB, icb = s % ICB;
        const int kh = (TAPS == 9) ? (tap / 3 - 1) : 0;
        const int kw = (TAPS == 9) ? (tap % 3 - 1) : 0;
        const int r = h + kh * DIL;
        if ((unsigned)r < 256u) {   // wave-uniform row bound (zero-pad semantics)
            short8 a0 = *(const short8*)(apack + ((size_t)(s * 2 + 0) * 64 + lane) * 8);
            short8 a1 = *(const short8*)(apack + ((size_t)(s * 2 + 1) * 64 + lane) * 8);
            const u16* src = TWO ? (icb ? in1 : in0) : in0;
            const int icoff = TWO ? 0 : icb * 32;
            size_t base = ((size_t)b * HPW + (size_t)r * PW + PAD + nl + kw * DIL) * CS
                          + icoff + icg * 8;
            #pragma unroll
            for (int nf = 0; nf < 4; ++nf) {
                short8 bf = *(const short8*)(src + base + (size_t)nf * 16 * CS);
                acc[0][nf] = __builtin_amdgcn_mfma_f32_16x16x32_bf16(a0, bf, acc[0][nf], 0, 0, 0);
                acc[1][nf] = __builtin_amdgcn_mfma_f32_16x16x32_bf16(a1, bf, acc[1][nf], 0, 0, 0);
            }
        }
    }
    // C/D: col(=px) = lane&15, row(=co) = icg*4 + i  (verified m89 mapping)
    const size_t orow = ((size_t)b * HPW + (size_t)h * PW + PAD) * 32;
    #pragma unroll
    for (int mf = 0; mf < 2; ++mf) {
        const int cob = mf * 16 + icg * 4;
        f32x4 bi = *(const f32x4*)(bias + cob);
        #pragma unroll
        for (int nf = 0; nf < 4; ++nf) {
            ushort4v o;
            #pragma unroll
            for (int i = 0; i < 4; ++i) {
                float v = acc[mf][nf][i] + bi[i];
                if (ACT == 1) v = fmaxf(v, 0.f);
                if (ACT == 2) v = (v > 0.f) ? v : 0.01f * v;
                o[i] = f2bf(v);
            }
            *(ushort4v*)(out + orow + (size_t)(nl + nf * 16) * 32 + cob) = o;
        }
    }
}

// ---------------- weight prepack (all conv layers -> fragment order) -------
__global__ void prepack_k(
    const float* __restrict__ f4w, const float* __restrict__ e1w,
    const float* __restrict__ e2w, const float* __restrict__ e3w,
    const float* __restrict__ f1w, const float* __restrict__ f2w,
    const float* __restrict__ f3w, const float* __restrict__ p1w,
    const float* __restrict__ p2w, const float* __restrict__ p3w,
    u16* __restrict__ apack)
{
    int gid = blockIdx.x * 256 + threadIdx.x;
    if (gid >= 77 * 1024) return;
    const int offs[11] = {0, 18, 27, 36, 45, 54, 63, 72, 73, 75, 77};
    int step = gid >> 10, r = gid & 1023;
    int layer = 0;
    while (step >= offs[layer + 1]) layer++;
    int s = step - offs[layer];
    int mf = r >> 9, l = (r >> 3) & 63, j = r & 7;
    int co = mf * 16 + (l & 15);
    int ICB = (layer == 0 || layer == 8 || layer == 9) ? 2 : 1;
    int tap = s / ICB, icb = s % ICB;
    int icl = icb * 32 + (l >> 4) * 8 + j;
    float v = 0.f;
    if (layer == 0)      { if (icl < 33) v = f4w[(co * 33 + icl) * 9 + tap]; }
    else if (layer == 1) v = e1w[(co * 32 + icl) * 9 + tap];
    else if (layer == 2) v = e2w[(co * 32 + icl) * 9 + tap];
    else if (layer == 3) v = e3w[(co * 32 + icl) * 9 + tap];
    else if (layer == 4) v = f1w[(co * 32 + icl) * 9 + tap];
    else if (layer == 5) v = f2w[(co * 32 + icl) * 9 + tap];
    else if (layer == 6) v = f3w[(co * 32 + icl) * 9 + tap];
    else if (layer == 7) v = p1w[co * 32 + icl];
    else if (layer == 8) v = p2w[co * 64 + icl];
    else                 v = p3w[co * 64 + icl];
    apack[gid] = f2bf(v);
}

// ---------------- zero the W-pad border columns of a padded NHWC buffer ----
__global__ void bzero_k(u16* __restrict__ buf, int C, int total)
{
    int idx = blockIdx.x * 256 + threadIdx.x;
    if (idx >= total) return;
    int c = idx % C, r = idx / C;
    int col6 = r % 6, h = (r / 6) & 255, b = r / (6 * 256);
    int col = (col6 < 3) ? col6 : (256 + PAD + col6 - 3);
    buf[((size_t)b * HPW + (size_t)h * PW + col) * C + c] = 0;
}

// ---------------- sobel conv (1ch in) + build 64-ch f4 input ---------------
// F4IN ch0 = x, ch1..32 = sobel out0, ch33..63 = 0.  (concat([x, out0]))
__global__ __launch_bounds__(256) void sobel_f4in_k(
    const float* __restrict__ x, const float* __restrict__ sbase,
    const float* __restrict__ sfac, const float* __restrict__ sbias,
    u16* __restrict__ f4in)
{
    __shared__ float sw[288];
    __shared__ float sb[32];
    int tid = threadIdx.x;
    for (int i = tid; i < 288; i += 256) sw[i] = sbase[i] * sfac[i / 9];
    if (tid < 32) sb[tid] = sbias[tid];
    __syncthreads();
    int gid = blockIdx.x * 256 + tid;
    int b = gid >> 16, hw = gid & 65535, h = hw >> 8, w = hw & 255;
    const float* xp = x + (size_t)b * 65536;
    float xv[9];
    #pragma unroll
    for (int kh = 0; kh < 3; ++kh)
        #pragma unroll
        for (int kw = 0; kw < 3; ++kw) {
            int rr = h + kh - 1, cc = w + kw - 1;
            xv[kh * 3 + kw] = ((unsigned)rr < 256u && (unsigned)cc < 256u)
                              ? xp[rr * 256 + cc] : 0.f;
        }
    u16 och[64];
    och[0] = f2bf(xv[4]);
    #pragma unroll
    for (int c = 0; c < 32; ++c) {
        float s = sb[c];
        #pragma unroll
        for (int t = 0; t < 9; ++t) s = fmaf(sw[c * 9 + t], xv[t], s);
        och[1 + c] = f2bf(s);
    }
    #pragma unroll
    for (int c = 33; c < 64; ++c) och[c] = 0;
    u16* dst = f4in + ((size_t)b * HPW + (size_t)h * PW + PAD + w) * 64;
    #pragma unroll
    for (int k = 0; k < 8; ++k)
        *(short8*)(dst + k * 8) = *(short8*)(&och[k * 8]);
}

// ---------------- gate softmax + blend (two-pass, in place into e1) --------
__global__ __launch_bounds__(256) void fuse_k(
    u16* __restrict__ e1, const u16* __restrict__ e2, const u16* __restrict__ e3,
    const float* __restrict__ gw_, const float* __restrict__ gb_)
{
    __shared__ float gw[288];
    __shared__ float gb[3];
    int tid = threadIdx.x;
    for (int i = tid; i < 288; i += 256) gw[i] = gw_[i];
    if (tid < 3) gb[tid] = gb_[tid];
    __syncthreads();
    int gid = blockIdx.x * 256 + tid;
    int b = gid >> 16, hw = gid & 65535, h = hw >> 8, w = hw & 255;
    size_t off = ((size_t)b * HPW + (size_t)h * PW + PAD + w) * 32;
    float g0 = gb[0], g1 = gb[1], g2 = gb[2];
    #pragma unroll
    for (int cb = 0; cb < 4; ++cb) {
        short8 v1 = *(const short8*)(e1 + off + cb * 8);
        short8 v2 = *(const short8*)(e2 + off + cb * 8);
        short8 v3 = *(const short8*)(e3 + off + cb * 8);
        #pragma unroll
        for (int j = 0; j < 8; ++j) {
            int c = cb * 8 + j;
            float fx = bf2f((u16)v1[j]), fy = bf2f((u16)v2[j]), fz = bf2f((u16)v3[j]);
            g0 = fmaf(gw[c], fx, g0);      g0 = fmaf(gw[32 + c], fy, g0);  g0 = fmaf(gw[64 + c], fz, g0);
            g1 = fmaf(gw[96 + c], fx, g1); g1 = fmaf(gw[128 + c], fy, g1); g1 = fmaf(gw[160 + c], fz, g1);
            g2 = fmaf(gw[192 + c], fx, g2);g2 = fmaf(gw[224 + c], fy, g2); g2 = fmaf(gw[256 + c], fz, g2);
        }
    }
    float m = fmaxf(g0, fmaxf(g1, g2));
    float e0 = expf(g0 - m), ee1 = expf(g1 - m), ee2 = expf(g2 - m);
    float inv = 1.f / (e0 + ee1 + ee2);
    e0 *= inv; ee1 *= inv; ee2 *= inv;
    #pragma unroll
    for (int cb = 0; cb < 4; ++cb) {
        short8 v1 = *(const short8*)(e1 + off + cb * 8);
        short8 v2 = *(const short8*)(e2 + off + cb * 8);
        short8 v3 = *(const short8*)(e3 + off + cb * 8);
        short8 o;
        #pragma unroll
        for (int j = 0; j < 8; ++j) {
            float blend = e0 * bf2f((u16)v1[j]) + ee1 * bf2f((u16)v2[j]) + ee2 * bf2f((u16)v3[j]);
            o[j] = (short)f2bf(blend);
        }
        *(short8*)(e1 + off + cb * 8) = o;
    }
}

// ---------------- channel attention: partial reduce over px ----------------
__global__ __launch_bounds__(256) void ca_part_k(
    const u16* __restrict__ enh, float* __restrict__ part)
{
    int blk = blockIdx.x, b = blk >> 5, sl = blk & 31;
    int tid = threadIdx.x, lane = tid & 63, wv = tid >> 6;
    float s[32], m[32];
    #pragma unroll
    for (int c = 0; c < 32; ++c) { s[c] = 0.f; m[c] = -1e30f; }
    for (int k = 0; k < 8; ++k) {
        int px = sl * 2048 + k * 256 + tid;
        int h = px >> 8, w = px & 255;
        size_t off = ((size_t)b * HPW + (size_t)h * PW + PAD + w) * 32;
        #pragma unroll
        for (int cb = 0; cb < 4; ++cb) {
            short8 v = *(const short8*)(enh + off + cb * 8);
            #pragma unroll
            for (int j = 0; j < 8; ++j) {
                float f = bf2f((u16)v[j]);
                s[cb * 8 + j] += f;
                m[cb * 8 + j] = fmaxf(m[cb * 8 + j], f);
            }
        }
    }
    #pragma unroll
    for (int c = 0; c < 32; ++c)
        #pragma unroll
        for (int o = 32; o; o >>= 1) {
            s[c] += __shfl_down(s[c], o);
            m[c] = fmaxf(m[c], __shfl_down(m[c], o));
        }
    __shared__ float ls[4][32], lm[4][32];
    if (lane == 0)
        for (int c = 0; c < 32; ++c) { ls[wv][c] = s[c]; lm[wv][c] = m[c]; }
    __syncthreads();
    if (tid < 32) {
        float ts = 0.f, tm = -1e30f;
        for (int w2 = 0; w2 < 4; ++w2) { ts += ls[w2][tid]; tm = fmaxf(tm, lm[w2][tid]); }
        int bs = b * 32 + sl;
        part[(size_t)(bs * 2 + 0) * 32 + tid] = ts;
        part[(size_t)(bs * 2 + 1) * 32 + tid] = tm;
    }
}

// ---------------- CA final reduce + MLP + sigmoid --------------------------
__global__ void ca_final_k(const float* __restrict__ part,
                           const float* __restrict__ w1, const float* __restrict__ w2,
                           float* __restrict__ ca)
{
    int t = threadIdx.x, b = t >> 5, c = t & 31;
    float s = 0.f, m = -1e30f;
    for (int sl = 0; sl < 32; ++sl) {
        int bs = b * 32 + sl;
        s += part[(size_t)(bs * 2 + 0) * 32 + c];
        m = fmaxf(m, part[(size_t)(bs * 2 + 1) * 32 + c]);
    }
    __shared__ float av[8][32], mx[8][32];
    av[b][c] = s * (1.f / 65536.f);
    mx[b][c] = m;
    __syncthreads();
    float h0 = 0.f, h1 = 0.f;
    {
        float sa0 = 0.f, sm0 = 0.f, sa1 = 0.f, sm1 = 0.f;
        for (int k = 0; k < 32; ++k) {
            float wa = w1[k], wb = w1[32 + k];
            sa0 = fmaf(wa, av[b][k], sa0); sm0 = fmaf(wa, mx[b][k], sm0);
            sa1 = fmaf(wb, av[b][k], sa1); sm1 = fmaf(wb, mx[b][k], sm1);
        }
        h0 = fmaxf(sa0, 0.f) + fmaxf(sm0, 0.f);
        h1 = fmaxf(sa1, 0.f) + fmaxf(sm1, 0.f);
    }
    ca[t] = sigm(w2[c * 2 + 0] * h0 + w2[c * 2 + 1] * h1);
}

// ---------------- spatial-attention input maps (padded, borders zeroed) ----
__global__ __launch_bounds__(256) void samap_k(
    const u16* __restrict__ enh, const float* __restrict__ ca,
    float* __restrict__ smap)
{
    __shared__ float sca[256];
    int tid = threadIdx.x;
    sca[tid] = ca[tid];
    __syncthreads();
    int idx = blockIdx.x * 256 + tid;
    if (idx >= Bb * 262 * 262) return;
    int b = idx / (262 * 262), r = idx % (262 * 262);
    int ph = r / 262, pw = r % 262;
    float mean = 0.f, mxv = 0.f;
    if (ph >= 3 && ph < 259 && pw >= 3 && pw < 259) {
        int h = ph - 3, w = pw - 3;
        size_t off = ((size_t)b * HPW + (size_t)h * PW + PAD + w) * 32;
        float s = 0.f, m = -1e30f;
        #pragma unroll
        for (int cb = 0; cb < 4; ++cb) {
            short8 v = *(const short8*)(enh + off + cb * 8);
            #pragma unroll
            for (int j = 0; j < 8; ++j) {
                float f = bf2f((u16)v[j]) * sca[b * 32 + cb * 8 + j];
                s += f; m = fmaxf(m, f);
            }
        }
        mean = s * (1.f / 32.f); mxv = m;
    }
    smap[((size_t)b * 262 * 262 + (size_t)ph * 262 + pw) * 2 + 0] = mean;
    smap[((size_t)b * 262 * 262 + (size_t)ph * 262 + pw) * 2 + 1] = mxv;
}

// ---------------- 7x7 SA conv + sigmoid + residual merge -> out0 ----------
__global__ __launch_bounds__(256) void merge_k(
    const float* __restrict__ smap, const float* __restrict__ saw,
    const float* __restrict__ ca, const u16* __restrict__ out1,
    const u16* __restrict__ enh, u16* __restrict__ o0)
{
    __shared__ float sw[98];
    __shared__ float sca[256];
    int tid = threadIdx.x;
    for (int i = tid; i < 98; i += 256) sw[i] = saw[i];
    sca[tid] = ca[tid];
    __syncthreads();
    int gid = blockIdx.x * 256 + tid;
    int b = gid >> 16, hw = gid & 65535, h = hw >> 8, w = hw & 255;
    const float* sp = smap + (size_t)b * 262 * 262 * 2;
    float acc = 0.f;
    #pragma unroll
    for (int kh = 0; kh < 7; ++kh)
        #pragma unroll
        for (int kw = 0; kw < 7; ++kw) {
            const float* q = sp + ((size_t)(h + kh) * 262 + (w + kw)) * 2;
            acc = fmaf(q[0], sw[kh * 7 + kw], acc);
            acc = fmaf(q[1], sw[49 + kh * 7 + kw], acc);
        }
    float sa = sigm(acc);
    size_t off = ((size_t)b * HPW + (size_t)h * PW + PAD + w) * 32;
    #pragma unroll
    for (int cb = 0; cb < 4; ++cb) {
        short8 ve = *(const short8*)(enh + off + cb * 8);
        short8 vo = *(const short8*)(out1 + off + cb * 8);
        short8 o;
        #pragma unroll
        for (int j = 0; j < 8; ++j) {
            float f = sca[b * 32 + cb * 8 + j] * bf2f((u16)ve[j]);
            float v = bf2f((u16)vo[j]) + sa * f;
            v = (v > 0.f) ? v : 0.01f * v;
            o[j] = (short)f2bf(v);
        }
        *(short8*)(o0 + off + cb * 8) = o;
    }
}

// ---------------- final convert: NHWC bf16 (o0,t3) -> NCHW f32 d_out -------
__global__ __launch_bounds__(256) void convert_k(
    const u16* __restrict__ o0, const u16* __restrict__ t3,
    float* __restrict__ dout)
{
    int gid = blockIdx.x * 256 + threadIdx.x;
    int b = gid >> 16, hw = gid & 65535, h = hw >> 8, w = hw & 255;
    size_t off = ((size_t)b * HPW + (size_t)h * PW + PAD + w) * 32;
    float* dp = dout + (size_t)b * 64 * 65536 + hw;
    #pragma unroll
    for (int cb = 0; cb < 4; ++cb) {
        short8 v = *(const short8*)(o0 + off + cb * 8);
        #pragma unroll
        for (int j = 0; j < 8; ++j)
            dp[(size_t)(cb * 8 + j) * 65536] = bf2f((u16)v[j]);
    }
    #pragma unroll
    for (int cb = 0; cb < 4; ++cb) {
        short8 v = *(const short8*)(t3 + off + cb * 8);
        #pragma unroll
        for (int j = 0; j < 8; ++j)
            dp[(size_t)(32 + cb * 8 + j) * 65536] = bf2f((u16)v[j]);
    }
}

extern "C" void kernel_launch(void* const* d_in, const int* in_sizes, int n_in,
                              void* d_out, int out_size, void* d_ws, size_t ws_size,
                              hipStream_t stream)
{
    (void)in_sizes; (void)n_in; (void)out_size; (void)ws_size;
    const float* x        = (const float*)d_in[0];
    const float* sob_base = (const float*)d_in[1];
    const float* sob_fac  = (const float*)d_in[2];
    const float* sob_bias = (const float*)d_in[3];
    const float* f4_w = (const float*)d_in[4];   const float* f4_b = (const float*)d_in[5];
    const float* ec1_w = (const float*)d_in[6];  const float* ec1_b = (const float*)d_in[7];
    const float* ec2_w = (const float*)d_in[8];  const float* ec2_b = (const float*)d_in[9];
    const float* ec3_w = (const float*)d_in[10]; const float* ec3_b = (const float*)d_in[11];
    const float* gate_w = (const float*)d_in[12]; const float* gate_b = (const float*)d_in[13];
    const float* ca1_w = (const float*)d_in[14]; const float* ca2_w = (const float*)d_in[15];
    const float* sa_w  = (const float*)d_in[16];
    const float* p1_w = (const float*)d_in[17]; const float* p1_b = (const float*)d_in[18];
    const float* f1_w = (const float*)d_in[19]; const float* f1_b = (const float*)d_in[20];
    const float* p2_w = (const float*)d_in[21]; const float* p2_b = (const float*)d_in[22];
    const float* f2_w = (const float*)d_in[23]; const float* f2_b = (const float*)d_in[24];
    const float* p3_w = (const float*)d_in[25]; const float* p3_b = (const float*)d_in[26];
    const float* f3_w = (const float*)d_in[27]; const float* f3_b = (const float*)d_in[28];

    const size_t PB32 = (size_t)Bb * HPW * 32 * 2;  // padded 32-ch bf16 buffer bytes
    char* ws = (char*)d_ws;
    u16* OUT1 = (u16*)(ws);                 // also reused as Q in the cascade
    u16* O0   = (u16*)(ws + PB32);
    u16* T    = (u16*)(ws + 2 * PB32);
    u16* AP   = (u16*)(ws + 3 * PB32);      // 77*1024 bf16
    float* PART = (float*)(ws + 3 * PB32 + 77 * 1024 * 2);   // 8*32*2*32 f32
    float* CA   = (float*)(ws + 3 * PB32 + 77 * 1024 * 2 + 65536);

    char* doutc = (char*)d_out;
    u16* F4IN = (u16*)(doutc);              // 64-ch padded, dead after f4
    u16* E1   = (u16*)(doutc);              // then ENH in place
    u16* E2   = (u16*)(doutc + PB32);
    u16* E3   = (u16*)(doutc + 2 * PB32);
    float* SMAP = (float*)(doutc + 3 * PB32);  // 8*262*262*2 f32
    float* dout = (float*)d_out;

    dim3 blk(256);
    const int gpx = 2048;  // B*H blocks (also B*HW/256 pixel blocks)

    // weight prepack + border zeroing
    prepack_k<<<308, blk, 0, stream>>>(f4_w, ec1_w, ec2_w, ec3_w, f1_w, f2_w, f3_w,
                                       p1_w, p2_w, p3_w, AP);
    bzero_k<<<3072, blk, 0, stream>>>(F4IN, 64, Bb * 256 * 6 * 64);
    bzero_k<<<1536, blk, 0, stream>>>(OUT1, 32, Bb * 256 * 6 * 32);
    // sobel + f4-input build
    sobel_f4in_k<<<gpx, blk, 0, stream>>>(x, sob_base, sob_fac, sob_bias, F4IN);
    // f4: 64ch x 3x3 -> OUT1 (lrelu)
    convm_k<9, 2, 1, 2, false><<<gpx, blk, 0, stream>>>(F4IN, nullptr, AP + 0 * 1024, f4_b, OUT1);
    // dilated edge convs (relu)
    convm_k<9, 1, 1, 1, false><<<gpx, blk, 0, stream>>>(OUT1, nullptr, AP + 18 * 1024, ec1_b, E1);
    convm_k<9, 1, 2, 1, false><<<gpx, blk, 0, stream>>>(OUT1, nullptr, AP + 27 * 1024, ec2_b, E2);
    convm_k<9, 1, 3, 1, false><<<gpx, blk, 0, stream>>>(OUT1, nullptr, AP + 36 * 1024, ec3_b, E3);
    // gate softmax + blend -> ENH (in place in E1)
    fuse_k<<<gpx, blk, 0, stream>>>(E1, E2, E3, gate_w, gate_b);
    // channel attention
    ca_part_k<<<256, blk, 0, stream>>>(E1, PART);
    ca_final_k<<<1, blk, 0, stream>>>(PART, ca1_w, ca2_w, CA);
    // spatial attention + merge -> O0
    samap_k<<<2146, blk, 0, stream>>>(E1, CA, SMAP);
    merge_k<<<gpx, blk, 0, stream>>>(SMAP, sa_w, CA, OUT1, E1, O0);
    // cascade (Q reuses OUT1's buffer; borders still zero)
    u16* Q = OUT1;
    convm_k<1, 1, 1, 2, false><<<gpx, blk, 0, stream>>>(O0, nullptr, AP + 72 * 1024, p1_b, Q);
    convm_k<9, 1, 1, 2, false><<<gpx, blk, 0, stream>>>(Q, nullptr, AP + 45 * 1024, f1_b, T);
    convm_k<1, 2, 1, 2, true ><<<gpx, blk, 0, stream>>>(O0, T, AP + 73 * 1024, p2_b, Q);
    convm_k<9, 1, 1, 2, false><<<gpx, blk, 0, stream>>>(Q, nullptr, AP + 54 * 1024, f2_b, T);
    convm_k<1, 2, 1, 2, true ><<<gpx, blk, 0, stream>>>(O0, T, AP + 75 * 1024, p3_b, Q);
    convm_k<9, 1, 1, 2, false><<<gpx, blk, 0, stream>>>(Q, nullptr, AP + 63 * 1024, f3_b, T);
    // final layout conversion
    convert_k<<<gpx, blk, 0, stream>>>(O0, T, dout);
}

// Round 4
// 503.251 us; speedup vs baseline: 18.7200x; 1.0688x over previous
//
#include <hip/hip_runtime.h>
#include <math.h>

typedef unsigned short u16;
typedef short short8 __attribute__((ext_vector_type(8)));
typedef float f32x4 __attribute__((ext_vector_type(4)));
typedef unsigned short ushort4v __attribute__((ext_vector_type(4)));

#define Hh 256
#define Ww 256
#define Bb 8
#define PW 262
#define PAD 3
#define HPW (Hh * PW)

__device__ __forceinline__ float bf2f(u16 v) {
    unsigned u = ((unsigned)v) << 16;
    union { unsigned u; float f; } c; c.u = u; return c.f;
}
__device__ __forceinline__ u16 f2bf(float f) {
    union { float f; unsigned u; } c; c.f = f;
    unsigned lsb = (c.u >> 16) & 1u;
    c.u += 0x7fffu + lsb;
    return (u16)(c.u >> 16);
}
__device__ __forceinline__ float sigm(float v) { return 1.f / (1.f + expf(-v)); }

// ============ strip 3x3 conv: 4 rows/block, A hoisted, XCD-swizzled =======
// grid 512 = B(8) * strips(64).  F32OUT: write d_out NCHW f32 at ch 32..63.
template<int ICB, int DIL, int ACT, bool F32OUT>
__global__ __launch_bounds__(256) void convs_k(
    const u16* __restrict__ in, const u16* __restrict__ apack,
    const float* __restrict__ bias, void* __restrict__ outp)
{
    constexpr int CS = ICB * 32;
    const int tid = threadIdx.x, lane = tid & 63, wv = tid >> 6;
    const int bid = ((blockIdx.x & 7) << 6) | (blockIdx.x >> 3);
    const int b = bid >> 6, hs = bid & 63;
    const int nl = (wv << 6) + (lane & 15);
    const int icg = lane >> 4;

    short8 A0[9 * ICB], A1[9 * ICB];
    #pragma unroll
    for (int s = 0; s < 9 * ICB; ++s) {
        A0[s] = *(const short8*)(apack + ((size_t)(s * 2 + 0) * 64 + lane) * 8);
        A1[s] = *(const short8*)(apack + ((size_t)(s * 2 + 1) * 64 + lane) * 8);
    }
    f32x4 bi[2];
    bi[0] = *(const f32x4*)(bias + icg * 4);
    bi[1] = *(const f32x4*)(bias + 16 + icg * 4);

    #pragma unroll 1
    for (int hh = 0; hh < 4; ++hh) {
        const int h = hs * 4 + hh;
        f32x4 acc[2][4];
        #pragma unroll
        for (int mf = 0; mf < 2; ++mf)
            #pragma unroll
            for (int nf = 0; nf < 4; ++nf)
                acc[mf][nf] = (f32x4){0.f, 0.f, 0.f, 0.f};
        #pragma unroll
        for (int s = 0; s < 9 * ICB; ++s) {
            const int tap = s / ICB, icb = s % ICB;
            const int kh = tap / 3 - 1, kw = tap % 3 - 1;
            const int r = h + kh * DIL;
            if ((unsigned)r < 256u) {
                size_t base = ((size_t)b * HPW + (size_t)r * PW + PAD + nl + kw * DIL) * CS
                              + icb * 32 + icg * 8;
                #pragma unroll
                for (int nf = 0; nf < 4; ++nf) {
                    short8 bf = *(const short8*)(in + base + (size_t)nf * 16 * CS);
                    acc[0][nf] = __builtin_amdgcn_mfma_f32_16x16x32_bf16(A0[s], bf, acc[0][nf], 0, 0, 0);
                    acc[1][nf] = __builtin_amdgcn_mfma_f32_16x16x32_bf16(A1[s], bf, acc[1][nf], 0, 0, 0);
                }
            }
        }
        if (F32OUT) {
            float* dp = (float*)outp + ((size_t)b * 64 + 32) * 65536 + (size_t)h * 256;
            #pragma unroll
            for (int mf = 0; mf < 2; ++mf) {
                const int cob = mf * 16 + icg * 4;
                #pragma unroll
                for (int nf = 0; nf < 4; ++nf) {
                    const int w = nl + nf * 16;
                    #pragma unroll
                    for (int i = 0; i < 4; ++i) {
                        float v = acc[mf][nf][i] + bi[mf][i];
                        if (ACT == 1) v = fmaxf(v, 0.f);
                        if (ACT == 2) v = (v > 0.f) ? v : 0.01f * v;
                        dp[(size_t)(cob + i) * 65536 + w] = v;
                    }
                }
            }
        } else {
            const size_t orow = ((size_t)b * HPW + (size_t)h * PW + PAD) * 32;
            u16* out = (u16*)outp;
            #pragma unroll
            for (int mf = 0; mf < 2; ++mf) {
                const int cob = mf * 16 + icg * 4;
                #pragma unroll
                for (int nf = 0; nf < 4; ++nf) {
                    ushort4v o;
                    #pragma unroll
                    for (int i = 0; i < 4; ++i) {
                        float v = acc[mf][nf][i] + bi[mf][i];
                        if (ACT == 1) v = fmaxf(v, 0.f);
                        if (ACT == 2) v = (v > 0.f) ? v : 0.01f * v;
                        o[i] = f2bf(v);
                    }
                    *(ushort4v*)(out + orow + (size_t)(nl + nf * 16) * 32 + cob) = o;
                }
            }
        }
    }
}

// ============ fused ec1/ec2/ec3 + gate softmax + blend -> ENH =============
// apack: 27 contiguous steps (ec1 d1, ec2 d2, ec3 d3). grid 512.
__global__ __launch_bounds__(256) void ecfuse_k(
    const u16* __restrict__ in, const u16* __restrict__ apack,
    const float* __restrict__ b1, const float* __restrict__ b2,
    const float* __restrict__ b3, const float* __restrict__ gw_,
    const float* __restrict__ gb_, u16* __restrict__ enh)
{
    __shared__ float gw[288];
    __shared__ float gb[3];
    __shared__ float bs[96];
    int tid = threadIdx.x;
    for (int i = tid; i < 288; i += 256) gw[i] = gw_[i];
    if (tid < 3) gb[tid] = gb_[tid];
    if (tid < 32) bs[tid] = b1[tid];
    else if (tid < 64) bs[tid] = b2[tid - 32];
    else if (tid < 96) bs[tid] = b3[tid - 64];
    __syncthreads();

    const int lane = tid & 63, wv = tid >> 6;
    const int bid = ((blockIdx.x & 7) << 6) | (blockIdx.x >> 3);
    const int b = bid >> 6, hs = bid & 63;
    const int nl = (wv << 6) + (lane & 15);
    const int icg = lane >> 4;

    #pragma unroll 1
    for (int hh = 0; hh < 4; ++hh) {
        const int h = hs * 4 + hh;
        f32x4 acc[3][2][4];
        #pragma unroll
        for (int cv = 0; cv < 3; ++cv)
            #pragma unroll
            for (int mf = 0; mf < 2; ++mf)
                #pragma unroll
                for (int nf = 0; nf < 4; ++nf)
                    acc[cv][mf][nf] = (f32x4){0.f, 0.f, 0.f, 0.f};
        #pragma unroll
        for (int cv = 0; cv < 3; ++cv) {
            const int dil = cv + 1;
            #pragma unroll
            for (int tap = 0; tap < 9; ++tap) {
                const int kh = tap / 3 - 1, kw = tap % 3 - 1;
                const int r = h + kh * dil;
                if ((unsigned)r < 256u) {
                    const int s = cv * 9 + tap;
                    short8 a0 = *(const short8*)(apack + ((size_t)(s * 2 + 0) * 64 + lane) * 8);
                    short8 a1 = *(const short8*)(apack + ((size_t)(s * 2 + 1) * 64 + lane) * 8);
                    size_t base = ((size_t)b * HPW + (size_t)r * PW + PAD + nl + kw * dil) * 32
                                  + icg * 8;
                    #pragma unroll
                    for (int nf = 0; nf < 4; ++nf) {
                        short8 bf = *(const short8*)(in + base + (size_t)nf * 16 * 32);
                        acc[cv][0][nf] = __builtin_amdgcn_mfma_f32_16x16x32_bf16(a0, bf, acc[cv][0][nf], 0, 0, 0);
                        acc[cv][1][nf] = __builtin_amdgcn_mfma_f32_16x16x32_bf16(a1, bf, acc[cv][1][nf], 0, 0, 0);
                    }
                }
            }
        }
        const size_t orow = ((size_t)b * HPW + (size_t)h * PW + PAD) * 32;
        #pragma unroll
        for (int nf = 0; nf < 4; ++nf) {
            // relu+bias -> e values; gate partials over this lane's 8 co x 3 convs
            float e[3][2][4];
            float g0 = 0.f, g1 = 0.f, g2 = 0.f;
            #pragma unroll
            for (int cv = 0; cv < 3; ++cv)
                #pragma unroll
                for (int mf = 0; mf < 2; ++mf) {
                    const int cob = mf * 16 + icg * 4;
                    #pragma unroll
                    for (int i = 0; i < 4; ++i) {
                        float v = fmaxf(acc[cv][mf][nf][i] + bs[cv * 32 + cob + i], 0.f);
                        e[cv][mf][i] = v;
                        const int c = cv * 32 + cob + i;
                        g0 = fmaf(gw[c], v, g0);
                        g1 = fmaf(gw[96 + c], v, g1);
                        g2 = fmaf(gw[192 + c], v, g2);
                    }
                }
            g0 += __shfl_xor(g0, 16); g0 += __shfl_xor(g0, 32);
            g1 += __shfl_xor(g1, 16); g1 += __shfl_xor(g1, 32);
            g2 += __shfl_xor(g2, 16); g2 += __shfl_xor(g2, 32);
            g0 += gb[0]; g1 += gb[1]; g2 += gb[2];
            float m = fmaxf(g0, fmaxf(g1, g2));
            float e0 = expf(g0 - m), e1 = expf(g1 - m), e2 = expf(g2 - m);
            float inv = 1.f / (e0 + e1 + e2);
            e0 *= inv; e1 *= inv; e2 *= inv;
            #pragma unroll
            for (int mf = 0; mf < 2; ++mf) {
                const int cob = mf * 16 + icg * 4;
                ushort4v o;
                #pragma unroll
                for (int i = 0; i < 4; ++i)
                    o[i] = f2bf(e0 * e[0][mf][i] + e1 * e[1][mf][i] + e2 * e[2][mf][i]);
                *(ushort4v*)(enh + orow + (size_t)(nl + nf * 16) * 32 + cob) = o;
            }
        }
    }
}

// ============ 1x1 conv (unchanged structure; fetch-optimal) ===============
template<int ICB, int ACT, bool TWO>
__global__ __launch_bounds__(256) void convm_k(
    const u16* __restrict__ in0, const u16* __restrict__ in1,
    const u16* __restrict__ apack, const float* __restrict__ bias,
    u16* __restrict__ out)
{
    constexpr int CS = TWO ? 32 : ICB * 32;
    const int tid = threadIdx.x, lane = tid & 63, wv = tid >> 6;
    const int h = blockIdx.x & 255, b = blockIdx.x >> 8;
    const int nl = (wv << 6) + (lane & 15);
    const int icg = lane >> 4;

    f32x4 acc[2][4];
    #pragma unroll
    for (int mf = 0; mf < 2; ++mf)
        #pragma unroll
        for (int nf = 0; nf < 4; ++nf)
            acc[mf][nf] = (f32x4){0.f, 0.f, 0.f, 0.f};

    #pragma unroll
    for (int s = 0; s < ICB; ++s) {
        short8 a0 = *(const short8*)(apack + ((size_t)(s * 2 + 0) * 64 + lane) * 8);
        short8 a1 = *(const short8*)(apack + ((size_t)(s * 2 + 1) * 64 + lane) * 8);
        const u16* src = TWO ? (s ? in1 : in0) : in0;
        const int icoff = TWO ? 0 : s * 32;
        size_t base = ((size_t)b * HPW + (size_t)h * PW + PAD + nl) * CS + icoff + icg * 8;
        #pragma unroll
        for (int nf = 0; nf < 4; ++nf) {
            short8 bf = *(const short8*)(src + base + (size_t)nf * 16 * CS);
            acc[0][nf] = __builtin_amdgcn_mfma_f32_16x16x32_bf16(a0, bf, acc[0][nf], 0, 0, 0);
            acc[1][nf] = __builtin_amdgcn_mfma_f32_16x16x32_bf16(a1, bf, acc[1][nf], 0, 0, 0);
        }
    }
    const size_t orow = ((size_t)b * HPW + (size_t)h * PW + PAD) * 32;
    #pragma unroll
    for (int mf = 0; mf < 2; ++mf) {
        const int cob = mf * 16 + icg * 4;
        f32x4 bi = *(const f32x4*)(bias + cob);
        #pragma unroll
        for (int nf = 0; nf < 4; ++nf) {
            ushort4v o;
            #pragma unroll
            for (int i = 0; i < 4; ++i) {
                float v = acc[mf][nf][i] + bi[i];
                if (ACT == 1) v = fmaxf(v, 0.f);
                if (ACT == 2) v = (v > 0.f) ? v : 0.01f * v;
                o[i] = f2bf(v);
            }
            *(ushort4v*)(out + orow + (size_t)(nl + nf * 16) * 32 + cob) = o;
        }
    }
}

// ============ weight prepack ==============================================
__global__ void prepack_k(
    const float* __restrict__ f4w, const float* __restrict__ e1w,
    const float* __restrict__ e2w, const float* __restrict__ e3w,
    const float* __restrict__ f1w, const float* __restrict__ f2w,
    const float* __restrict__ f3w, const float* __restrict__ p1w,
    const float* __restrict__ p2w, const float* __restrict__ p3w,
    u16* __restrict__ apack)
{
    int gid = blockIdx.x * 256 + threadIdx.x;
    if (gid >= 77 * 1024) return;
    const int offs[11] = {0, 18, 27, 36, 45, 54, 63, 72, 73, 75, 77};
    int step = gid >> 10, r = gid & 1023;
    int layer = 0;
    while (step >= offs[layer + 1]) layer++;
    int s = step - offs[layer];
    int mf = r >> 9, l = (r >> 3) & 63, j = r & 7;
    int co = mf * 16 + (l & 15);
    int ICB = (layer == 0 || layer == 8 || layer == 9) ? 2 : 1;
    int tap = s / ICB, icb = s % ICB;
    int icl = icb * 32 + (l >> 4) * 8 + j;
    float v = 0.f;
    if (layer == 0)      { if (icl < 33) v = f4w[(co * 33 + icl) * 9 + tap]; }
    else if (layer == 1) v = e1w[(co * 32 + icl) * 9 + tap];
    else if (layer == 2) v = e2w[(co * 32 + icl) * 9 + tap];
    else if (layer == 3) v = e3w[(co * 32 + icl) * 9 + tap];
    else if (layer == 4) v = f1w[(co * 32 + icl) * 9 + tap];
    else if (layer == 5) v = f2w[(co * 32 + icl) * 9 + tap];
    else if (layer == 6) v = f3w[(co * 32 + icl) * 9 + tap];
    else if (layer == 7) v = p1w[co * 32 + icl];
    else if (layer == 8) v = p2w[co * 64 + icl];
    else                 v = p3w[co * 64 + icl];
    apack[gid] = f2bf(v);
}

// ============ zero W-pad border columns ===================================
__global__ void bzero_k(u16* __restrict__ buf, int C, int total)
{
    int idx = blockIdx.x * 256 + threadIdx.x;
    if (idx >= total) return;
    int c = idx % C, r = idx / C;
    int col6 = r % 6, h = (r / 6) & 255, b = r / (6 * 256);
    int col = (col6 < 3) ? col6 : (256 + PAD + col6 - 3);
    buf[((size_t)b * HPW + (size_t)h * PW + col) * C + c] = 0;
}

// ============ sobel + f4-input build ======================================
__global__ __launch_bounds__(256) void sobel_f4in_k(
    const float* __restrict__ x, const float* __restrict__ sbase,
    const float* __restrict__ sfac, const float* __restrict__ sbias,
    u16* __restrict__ f4in)
{
    __shared__ float sw[288];
    __shared__ float sb[32];
    int tid = threadIdx.x;
    for (int i = tid; i < 288; i += 256) sw[i] = sbase[i] * sfac[i / 9];
    if (tid < 32) sb[tid] = sbias[tid];
    __syncthreads();
    int gid = blockIdx.x * 256 + tid;
    int b = gid >> 16, hw = gid & 65535, h = hw >> 8, w = hw & 255;
    const float* xp = x + (size_t)b * 65536;
    float xv[9];
    #pragma unroll
    for (int kh = 0; kh < 3; ++kh)
        #pragma unroll
        for (int kw = 0; kw < 3; ++kw) {
            int rr = h + kh - 1, cc = w + kw - 1;
            xv[kh * 3 + kw] = ((unsigned)rr < 256u && (unsigned)cc < 256u)
                              ? xp[rr * 256 + cc] : 0.f;
        }
    u16 och[64];
    och[0] = f2bf(xv[4]);
    #pragma unroll
    for (int c = 0; c < 32; ++c) {
        float s = sb[c];
        #pragma unroll
        for (int t = 0; t < 9; ++t) s = fmaf(sw[c * 9 + t], xv[t], s);
        och[1 + c] = f2bf(s);
    }
    #pragma unroll
    for (int c = 33; c < 64; ++c) och[c] = 0;
    u16* dst = f4in + ((size_t)b * HPW + (size_t)h * PW + PAD + w) * 64;
    #pragma unroll
    for (int k = 0; k < 8; ++k)
        *(short8*)(dst + k * 8) = *(short8*)(&och[k * 8]);
}

// ============ channel attention ===========================================
__global__ __launch_bounds__(256) void ca_part_k(
    const u16* __restrict__ enh, float* __restrict__ part)
{
    int blk = blockIdx.x, b = blk >> 5, sl = blk & 31;
    int tid = threadIdx.x, lane = tid & 63, wv = tid >> 6;
    float s[32], m[32];
    #pragma unroll
    for (int c = 0; c < 32; ++c) { s[c] = 0.f; m[c] = -1e30f; }
    for (int k = 0; k < 8; ++k) {
        int px = sl * 2048 + k * 256 + tid;
        int h = px >> 8, w = px & 255;
        size_t off = ((size_t)b * HPW + (size_t)h * PW + PAD + w) * 32;
        #pragma unroll
        for (int cb = 0; cb < 4; ++cb) {
            short8 v = *(const short8*)(enh + off + cb * 8);
            #pragma unroll
            for (int j = 0; j < 8; ++j) {
                float f = bf2f((u16)v[j]);
                s[cb * 8 + j] += f;
                m[cb * 8 + j] = fmaxf(m[cb * 8 + j], f);
            }
        }
    }
    #pragma unroll
    for (int c = 0; c < 32; ++c)
        #pragma unroll
        for (int o = 32; o; o >>= 1) {
            s[c] += __shfl_down(s[c], o);
            m[c] = fmaxf(m[c], __shfl_down(m[c], o));
        }
    __shared__ float ls[4][32], lm[4][32];
    if (lane == 0)
        for (int c = 0; c < 32; ++c) { ls[wv][c] = s[c]; lm[wv][c] = m[c]; }
    __syncthreads();
    if (tid < 32) {
        float ts = 0.f, tm = -1e30f;
        for (int w2 = 0; w2 < 4; ++w2) { ts += ls[w2][tid]; tm = fmaxf(tm, lm[w2][tid]); }
        int bs = b * 32 + sl;
        part[(size_t)(bs * 2 + 0) * 32 + tid] = ts;
        part[(size_t)(bs * 2 + 1) * 32 + tid] = tm;
    }
}

__global__ void ca_final_k(const float* __restrict__ part,
                           const float* __restrict__ w1, const float* __restrict__ w2,
                           float* __restrict__ ca)
{
    int t = threadIdx.x, b = t >> 5, c = t & 31;
    float s = 0.f, m = -1e30f;
    for (int sl = 0; sl < 32; ++sl) {
        int bs = b * 32 + sl;
        s += part[(size_t)(bs * 2 + 0) * 32 + c];
        m = fmaxf(m, part[(size_t)(bs * 2 + 1) * 32 + c]);
    }
    __shared__ float av[8][32], mx[8][32];
    av[b][c] = s * (1.f / 65536.f);
    mx[b][c] = m;
    __syncthreads();
    float sa0 = 0.f, sm0 = 0.f, sa1 = 0.f, sm1 = 0.f;
    for (int k = 0; k < 32; ++k) {
        float wa = w1[k], wb = w1[32 + k];
        sa0 = fmaf(wa, av[b][k], sa0); sm0 = fmaf(wa, mx[b][k], sm0);
        sa1 = fmaf(wb, av[b][k], sa1); sm1 = fmaf(wb, mx[b][k], sm1);
    }
    float h0 = fmaxf(sa0, 0.f) + fmaxf(sm0, 0.f);
    float h1 = fmaxf(sa1, 0.f) + fmaxf(sm1, 0.f);
    ca[t] = sigm(w2[c * 2 + 0] * h0 + w2[c * 2 + 1] * h1);
}

// ============ SA input maps (padded 262x262, borders zero) ================
__global__ __launch_bounds__(256) void samap_k(
    const u16* __restrict__ enh, const float* __restrict__ ca,
    float* __restrict__ smap)
{
    __shared__ float sca[256];
    int tid = threadIdx.x;
    sca[tid] = ca[tid];
    __syncthreads();
    int idx = blockIdx.x * 256 + tid;
    if (idx >= Bb * 262 * 262) return;
    int b = idx / (262 * 262), r = idx % (262 * 262);
    int ph = r / 262, pw = r % 262;
    float mean = 0.f, mxv = 0.f;
    if (ph >= 3 && ph < 259 && pw >= 3 && pw < 259) {
        int h = ph - 3, w = pw - 3;
        size_t off = ((size_t)b * HPW + (size_t)h * PW + PAD + w) * 32;
        float s = 0.f, m = -1e30f;
        #pragma unroll
        for (int cb = 0; cb < 4; ++cb) {
            short8 v = *(const short8*)(enh + off + cb * 8);
            #pragma unroll
            for (int j = 0; j < 8; ++j) {
                float f = bf2f((u16)v[j]) * sca[b * 32 + cb * 8 + j];
                s += f; m = fmaxf(m, f);
            }
        }
        mean = s * (1.f / 32.f); mxv = m;
    }
    smap[((size_t)b * 262 * 262 + (size_t)ph * 262 + pw) * 2 + 0] = mean;
    smap[((size_t)b * 262 * 262 + (size_t)ph * 262 + pw) * 2 + 1] = mxv;
}

// ============ 7x7 SA conv + merge -> O0 (bf16 NHWC) + d_out ch0-31 f32 ====
__global__ __launch_bounds__(256) void merge_k(
    const float* __restrict__ smap, const float* __restrict__ saw,
    const float* __restrict__ ca, const u16* __restrict__ out1,
    const u16* __restrict__ enh, u16* __restrict__ o0,
    float* __restrict__ dout)
{
    __shared__ float sw[98];
    __shared__ float sca[256];
    int tid = threadIdx.x;
    for (int i = tid; i < 98; i += 256) sw[i] = saw[i];
    sca[tid] = ca[tid];
    __syncthreads();
    int gid = blockIdx.x * 256 + tid;
    int b = gid >> 16, hw = gid & 65535, h = hw >> 8, w = hw & 255;
    const float* sp = smap + (size_t)b * 262 * 262 * 2;
    float acc = 0.f;
    #pragma unroll
    for (int kh = 0; kh < 7; ++kh)
        #pragma unroll
        for (int kw = 0; kw < 7; ++kw) {
            const float* q = sp + ((size_t)(h + kh) * 262 + (w + kw)) * 2;
            acc = fmaf(q[0], sw[kh * 7 + kw], acc);
            acc = fmaf(q[1], sw[49 + kh * 7 + kw], acc);
        }
    float sa = sigm(acc);
    size_t off = ((size_t)b * HPW + (size_t)h * PW + PAD + w) * 32;
    float* dp = dout + (size_t)b * 64 * 65536 + hw;
    #pragma unroll
    for (int cb = 0; cb < 4; ++cb) {
        short8 ve = *(const short8*)(enh + off + cb * 8);
        short8 vo = *(const short8*)(out1 + off + cb * 8);
        short8 o;
        #pragma unroll
        for (int j = 0; j < 8; ++j) {
            float f = sca[b * 32 + cb * 8 + j] * bf2f((u16)ve[j]);
            float v = bf2f((u16)vo[j]) + sa * f;
            v = (v > 0.f) ? v : 0.01f * v;
            o[j] = (short)f2bf(v);
            dp[(size_t)(cb * 8 + j) * 65536] = v;
        }
        *(short8*)(o0 + off + cb * 8) = o;
    }
}

extern "C" void kernel_launch(void* const* d_in, const int* in_sizes, int n_in,
                              void* d_out, int out_size, void* d_ws, size_t ws_size,
                              hipStream_t stream)
{
    (void)in_sizes; (void)n_in; (void)out_size; (void)ws_size;
    const float* x        = (const float*)d_in[0];
    const float* sob_base = (const float*)d_in[1];
    const float* sob_fac  = (const float*)d_in[2];
    const float* sob_bias = (const float*)d_in[3];
    const float* f4_w = (const float*)d_in[4];   const float* f4_b = (const float*)d_in[5];
    const float* ec1_w = (const float*)d_in[6];  const float* ec1_b = (const float*)d_in[7];
    const float* ec2_w = (const float*)d_in[8];  const float* ec2_b = (const float*)d_in[9];
    const float* ec3_w = (const float*)d_in[10]; const float* ec3_b = (const float*)d_in[11];
    const float* gate_w = (const float*)d_in[12]; const float* gate_b = (const float*)d_in[13];
    const float* ca1_w = (const float*)d_in[14]; const float* ca2_w = (const float*)d_in[15];
    const float* sa_w  = (const float*)d_in[16];
    const float* p1_w = (const float*)d_in[17]; const float* p1_b = (const float*)d_in[18];
    const float* f1_w = (const float*)d_in[19]; const float* f1_b = (const float*)d_in[20];
    const float* p2_w = (const float*)d_in[21]; const float* p2_b = (const float*)d_in[22];
    const float* f2_w = (const float*)d_in[23]; const float* f2_b = (const float*)d_in[24];
    const float* p3_w = (const float*)d_in[25]; const float* p3_b = (const float*)d_in[26];
    const float* f3_w = (const float*)d_in[27]; const float* f3_b = (const float*)d_in[28];

    const size_t PB32 = (size_t)Bb * HPW * 32 * 2;  // 34,340,864 B
    char* ws = (char*)d_ws;
    u16* Q    = (u16*)(ws);                 // out1, then cascade intermediates
    u16* O0   = (u16*)(ws + PB32);
    u16* T    = (u16*)(ws + 2 * PB32);
    u16* ENH  = (u16*)(ws + 3 * PB32);
    u16* AP   = (u16*)(ws + 4 * PB32);
    float* PART = (float*)(ws + 4 * PB32 + 77 * 1024 * 2);
    float* CA   = (float*)(ws + 4 * PB32 + 77 * 1024 * 2 + 65536);

    char* doutc = (char*)d_out;
    u16* F4IN = (u16*)(doutc);              // dead after f4 conv
    // SMAP parked in b=7 upper-half region of d_out (dead before f3 writes it)
    float* SMAP = (float*)(doutc + (134217728 - (size_t)Bb * 262 * 262 * 2 * 4));
    float* dout = (float*)d_out;

    dim3 blk(256);
    const int g_strip = 512;  // B * 64 strips (4 rows each), XCD-swizzled
    const int g_row = 2048;   // B * H

    prepack_k<<<308, blk, 0, stream>>>(f4_w, ec1_w, ec2_w, ec3_w, f1_w, f2_w, f3_w,
                                       p1_w, p2_w, p3_w, AP);
    bzero_k<<<3072, blk, 0, stream>>>(F4IN, 64, Bb * 256 * 6 * 64);
    bzero_k<<<1536, blk, 0, stream>>>(Q, 32, Bb * 256 * 6 * 32);
    sobel_f4in_k<<<g_row, blk, 0, stream>>>(x, sob_base, sob_fac, sob_bias, F4IN);
    // f4: 64ch 3x3 -> Q (out1, lrelu)
    convs_k<2, 1, 2, false><<<g_strip, blk, 0, stream>>>(F4IN, AP, f4_b, Q);
    // fused ec1/ec2/ec3 + gate + blend -> ENH
    ecfuse_k<<<g_strip, blk, 0, stream>>>(Q, AP + 18 * 1024, ec1_b, ec2_b, ec3_b,
                                          gate_w, gate_b, ENH);
    // channel attention
    ca_part_k<<<256, blk, 0, stream>>>(ENH, PART);
    ca_final_k<<<1, blk, 0, stream>>>(PART, ca1_w, ca2_w, CA);
    // spatial attention + merge (writes O0 bf16 + d_out ch0-31 f32)
    samap_k<<<2146, blk, 0, stream>>>(ENH, CA, SMAP);
    merge_k<<<g_row, blk, 0, stream>>>(SMAP, sa_w, CA, Q, ENH, O0, dout);
    // cascade
    convm_k<1, 2, false><<<g_row, blk, 0, stream>>>(O0, nullptr, AP + 72 * 1024, p1_b, Q);
    convs_k<1, 1, 2, false><<<g_strip, blk, 0, stream>>>(Q, AP + 45 * 1024, f1_b, T);
    convm_k<2, 2, true ><<<g_row, blk, 0, stream>>>(O0, T, AP + 73 * 1024, p2_b, Q);
    convs_k<1, 1, 2, false><<<g_strip, blk, 0, stream>>>(Q, AP + 54 * 1024, f2_b, T);
    convm_k<2, 2, true ><<<g_row, blk, 0, stream>>>(O0, T, AP + 75 * 1024, p3_b, Q);
    // f3 writes d_out ch32-63 f32 directly (also overwrites SMAP region - dead)
    convs_k<1, 1, 2, true ><<<g_strip, blk, 0, stream>>>(Q, AP + 63 * 1024, f3_b, dout);
}